// Round 1
// baseline (330.554 us; speedup 1.0000x reference)
//
#include <hip/hip_runtime.h>
#include <hip/hip_bf16.h>

// Bilinear edge scoring:  out[e] = x_source[src[e]] @ W @ x_target[tgt[e]] + b
// Factored as: Z = x_source @ W  (GEMM, 100000x128x128), then
//              out[e] = dot(Z[src[e]], x_target[tgt[e]]) + b.

#define D 128

// ---------------------------------------------------------------------------
// Kernel 1: Z = X @ W   (X: [N,128], W: [128,128], Z: [N,128]), fp32 vector ALU.
// Block = 256 threads, tile = 64 rows x 128 cols, each thread 4 rows x 8 cols.
// K is processed in two halves of 64 so static LDS stays ~50 KB (3 blocks/CU).
// ---------------------------------------------------------------------------
__global__ __launch_bounds__(256) void gemm_xw(const float* __restrict__ X,
                                               const float* __restrict__ W,
                                               float* __restrict__ Z, int N) {
    __shared__ float ws[64][128];   // W rows [h*64 .. h*64+63]
    __shared__ float xs[64][68];    // X tile cols [h*64 .. h*64+63], pad 68 (2-way max)

    const int tid = threadIdx.x;
    const int block_row = blockIdx.x * 64;
    const int tx = tid & 15;        // 16 col-groups
    const int ty = tid >> 4;        // 16 row-groups
    const int r0 = ty * 4;          // 4 rows per thread
    const int c0 = tx * 4;          // cols tx*4..+3 and 64+tx*4..+3 (2-way bank, free)
    const int c1 = 64 + tx * 4;

    float acc[4][8];
#pragma unroll
    for (int i = 0; i < 4; ++i)
#pragma unroll
        for (int j = 0; j < 8; ++j) acc[i][j] = 0.f;

    for (int h = 0; h < 2; ++h) {
        if (h) __syncthreads();     // protect LDS reuse across halves

        // stage W rows h*64..h*64+63  (64x128 f32 = 2048 float4, 8 per thread)
#pragma unroll
        for (int j = 0; j < 8; ++j) {
            int flat = j * 256 + tid;       // float4 index in 64x32
            int r = flat >> 5, cq = flat & 31;
            float4 w4 = ((const float4*)W)[(h * 64 + r) * 32 + cq];
            *(float4*)&ws[r][cq * 4] = w4;
        }
        // stage X tile cols h*64..h*64+63 (64x64 f32 = 1024 float4, 4 per thread)
#pragma unroll
        for (int j = 0; j < 4; ++j) {
            int flat = j * 256 + tid;       // float4 index in 64x16
            int r = flat >> 4, cq = flat & 15;
            int grow = block_row + r;
            float4 x4 = make_float4(0.f, 0.f, 0.f, 0.f);
            if (grow < N) x4 = ((const float4*)X)[grow * 32 + h * 16 + cq];
            *(float4*)&xs[r][cq * 4] = x4;
        }
        __syncthreads();

#pragma unroll 4
        for (int kk = 0; kk < 64; ++kk) {
            float4 w0 = *(const float4*)&ws[kk][c0];
            float4 w1 = *(const float4*)&ws[kk][c1];
            float xv0 = xs[r0 + 0][kk];
            float xv1 = xs[r0 + 1][kk];
            float xv2 = xs[r0 + 2][kk];
            float xv3 = xs[r0 + 3][kk];
            float xv[4] = {xv0, xv1, xv2, xv3};
#pragma unroll
            for (int i = 0; i < 4; ++i) {
                acc[i][0] += xv[i] * w0.x;
                acc[i][1] += xv[i] * w0.y;
                acc[i][2] += xv[i] * w0.z;
                acc[i][3] += xv[i] * w0.w;
                acc[i][4] += xv[i] * w1.x;
                acc[i][5] += xv[i] * w1.y;
                acc[i][6] += xv[i] * w1.z;
                acc[i][7] += xv[i] * w1.w;
            }
        }
    }

#pragma unroll
    for (int i = 0; i < 4; ++i) {
        int grow = block_row + r0 + i;
        if (grow < N) {
            float4 o0 = make_float4(acc[i][0], acc[i][1], acc[i][2], acc[i][3]);
            float4 o1 = make_float4(acc[i][4], acc[i][5], acc[i][6], acc[i][7]);
            *(float4*)&Z[(long long)grow * D + c0] = o0;
            *(float4*)&Z[(long long)grow * D + c1] = o1;
        }
    }
}

// ---------------------------------------------------------------------------
// Kernel 2: out[e] = dot(Z[src[e]], XT[tgt[e]]) + b
// 32 lanes per edge; each lane one float4 (512 B coalesced row read per operand),
// 5x shfl_xor reduce within the 32-lane half-wave. 2 edges per wave.
// ---------------------------------------------------------------------------
__global__ __launch_bounds__(256) void edge_score(const float* __restrict__ Z,
                                                  const float* __restrict__ XT,
                                                  const int* __restrict__ idx,
                                                  const float* __restrict__ bptr,
                                                  float* __restrict__ out, int E) {
    const float b = bptr[0];
    const int lane = threadIdx.x & 63;
    const int sub = lane >> 5;          // which edge of the wave's pair
    const int l = lane & 31;            // float4 slot within the 128-f row
    const int waveInBlock = threadIdx.x >> 6;
    const int waveGlobal = blockIdx.x * 4 + waveInBlock;
    const int totalWaves = gridDim.x * 4;
    const int nPairs = (E + 1) >> 1;

    for (int w = waveGlobal; w < nPairs; w += totalWaves) {
        int e = w * 2 + sub;
        float p = 0.f;
        if (e < E) {
            int s = idx[e];
            int t = idx[E + e];
            float4 a = ((const float4*)(Z + (long long)s * D))[l];
            float4 c = ((const float4*)(XT + (long long)t * D))[l];
            p = a.x * c.x + a.y * c.y + a.z * c.z + a.w * c.w;
        }
        p += __shfl_xor(p, 1, 64);
        p += __shfl_xor(p, 2, 64);
        p += __shfl_xor(p, 4, 64);
        p += __shfl_xor(p, 8, 64);
        p += __shfl_xor(p, 16, 64);
        if (l == 0 && e < E) out[e] = p + b;
    }
}

extern "C" void kernel_launch(void* const* d_in, const int* in_sizes, int n_in,
                              void* d_out, int out_size, void* d_ws, size_t ws_size,
                              hipStream_t stream) {
    const float* x_source = (const float*)d_in[0];
    const float* x_target = (const float*)d_in[1];
    const int* edge_idx = (const int*)d_in[2];
    const float* W = (const float*)d_in[3];
    const float* b = (const float*)d_in[4];
    float* out = (float*)d_out;
    float* Z = (float*)d_ws;                 // [N,128] f32 = 51.2 MB scratch

    const int N = in_sizes[0] / D;           // 100000
    const int E = in_sizes[2] / 2;           // 2000000

    // Z = x_source @ W
    int gemm_blocks = (N + 63) / 64;
    gemm_xw<<<gemm_blocks, 256, 0, stream>>>(x_source, W, Z, N);

    // edge scores
    int edge_blocks = 2048;                  // 8 blocks/CU, grid-stride
    edge_score<<<edge_blocks, 256, 0, stream>>>(Z, x_target, edge_idx, b, out, E);
}

// Round 2
// 203.012 us; speedup vs baseline: 1.6282x; 1.6282x over previous
//
#include <hip/hip_runtime.h>
#include <hip/hip_bf16.h>

// Bilinear edge scoring:  out[e] = x_source[src[e]] @ W @ x_target[tgt[e]] + b
// Factored: Z = x_source @ W (fp32 vector GEMM, bf16 output), XTb = bf16(x_target),
// then out[e] = dot_bf16(Zb[src[e]], XTb[tgt[e]]) + b with fp32 accumulation.
// Rationale: edge gather is L2-miss-path bound (995 MB fetch @3.6 TB/s); bf16
// halves gathered bytes and the working set.

#define D 128

__device__ __forceinline__ unsigned short f2bf_rn(float f) {
    unsigned int u = __float_as_uint(f);
    u += 0x7fff + ((u >> 16) & 1);          // round-to-nearest-even
    return (unsigned short)(u >> 16);
}

// ---------------------------------------------------------------------------
// Kernel 1: Zb = bf16(X @ W)   (X: [N,128], W: [128,128]), fp32 vector ALU.
// Block = 256 threads, tile = 64 rows x 128 cols, each thread 4 rows x 8 cols.
// ---------------------------------------------------------------------------
__global__ __launch_bounds__(256) void gemm_xw(const float* __restrict__ X,
                                               const float* __restrict__ W,
                                               unsigned short* __restrict__ Zb, int N) {
    __shared__ float ws[64][128];   // W rows [h*64 .. h*64+63]
    __shared__ float xs[64][68];    // X tile cols [h*64 .. h*64+63], padded

    const int tid = threadIdx.x;
    const int block_row = blockIdx.x * 64;
    const int tx = tid & 15;
    const int ty = tid >> 4;
    const int r0 = ty * 4;
    const int c0 = tx * 4;
    const int c1 = 64 + tx * 4;

    float acc[4][8];
#pragma unroll
    for (int i = 0; i < 4; ++i)
#pragma unroll
        for (int j = 0; j < 8; ++j) acc[i][j] = 0.f;

    for (int h = 0; h < 2; ++h) {
        if (h) __syncthreads();

#pragma unroll
        for (int j = 0; j < 8; ++j) {
            int flat = j * 256 + tid;
            int r = flat >> 5, cq = flat & 31;
            float4 w4 = ((const float4*)W)[(h * 64 + r) * 32 + cq];
            *(float4*)&ws[r][cq * 4] = w4;
        }
#pragma unroll
        for (int j = 0; j < 4; ++j) {
            int flat = j * 256 + tid;
            int r = flat >> 4, cq = flat & 15;
            int grow = block_row + r;
            float4 x4 = make_float4(0.f, 0.f, 0.f, 0.f);
            if (grow < N) x4 = ((const float4*)X)[grow * 32 + h * 16 + cq];
            *(float4*)&xs[r][cq * 4] = x4;
        }
        __syncthreads();

#pragma unroll 4
        for (int kk = 0; kk < 64; ++kk) {
            float4 w0 = *(const float4*)&ws[kk][c0];
            float4 w1 = *(const float4*)&ws[kk][c1];
            float xv[4] = {xs[r0 + 0][kk], xs[r0 + 1][kk], xs[r0 + 2][kk], xs[r0 + 3][kk]};
#pragma unroll
            for (int i = 0; i < 4; ++i) {
                acc[i][0] += xv[i] * w0.x;
                acc[i][1] += xv[i] * w0.y;
                acc[i][2] += xv[i] * w0.z;
                acc[i][3] += xv[i] * w0.w;
                acc[i][4] += xv[i] * w1.x;
                acc[i][5] += xv[i] * w1.y;
                acc[i][6] += xv[i] * w1.z;
                acc[i][7] += xv[i] * w1.w;
            }
        }
    }

#pragma unroll
    for (int i = 0; i < 4; ++i) {
        int grow = block_row + r0 + i;
        if (grow < N) {
            ushort4 p0 = make_ushort4(f2bf_rn(acc[i][0]), f2bf_rn(acc[i][1]),
                                      f2bf_rn(acc[i][2]), f2bf_rn(acc[i][3]));
            ushort4 p1 = make_ushort4(f2bf_rn(acc[i][4]), f2bf_rn(acc[i][5]),
                                      f2bf_rn(acc[i][6]), f2bf_rn(acc[i][7]));
            *(ushort4*)&Zb[(size_t)grow * D + c0] = p0;
            *(ushort4*)&Zb[(size_t)grow * D + c1] = p1;
        }
    }
}

// ---------------------------------------------------------------------------
// Kernel 2: streaming fp32 -> bf16 cast (8 elements / thread / iter)
// ---------------------------------------------------------------------------
__global__ __launch_bounds__(256) void cast_to_bf16(const float* __restrict__ in,
                                                    unsigned short* __restrict__ outb,
                                                    int n8) {
    int i = blockIdx.x * blockDim.x + threadIdx.x;
    const int stride = gridDim.x * blockDim.x;
    for (; i < n8; i += stride) {
        float4 a = ((const float4*)in)[2 * i];
        float4 c = ((const float4*)in)[2 * i + 1];
        uint4 o;
        o.x = (unsigned int)f2bf_rn(a.x) | ((unsigned int)f2bf_rn(a.y) << 16);
        o.y = (unsigned int)f2bf_rn(a.z) | ((unsigned int)f2bf_rn(a.w) << 16);
        o.z = (unsigned int)f2bf_rn(c.x) | ((unsigned int)f2bf_rn(c.y) << 16);
        o.w = (unsigned int)f2bf_rn(c.z) | ((unsigned int)f2bf_rn(c.w) << 16);
        ((uint4*)outb)[i] = o;
    }
}

// ---------------------------------------------------------------------------
// Kernel 3: out[e] = dot(Zb[src[e]], XTb[tgt[e]]) + b
// 16 lanes per edge; each lane one uint4 = 8 bf16 (256 B coalesced row read),
// 4x shfl_xor reduce. 4 edges per wave.
// ---------------------------------------------------------------------------
__global__ __launch_bounds__(256) void edge_score(const unsigned short* __restrict__ Zb,
                                                  const unsigned short* __restrict__ XTb,
                                                  const int* __restrict__ idx,
                                                  const float* __restrict__ bptr,
                                                  float* __restrict__ out, int E) {
    const float b = bptr[0];
    const int lane = threadIdx.x & 63;
    const int sub = lane >> 4;          // 4 edges per wave
    const int l = lane & 15;            // uint4 slot within the 256 B row
    const int waveGlobal = blockIdx.x * 4 + (threadIdx.x >> 6);
    const int totalWaves = gridDim.x * 4;
    const int nQuads = (E + 3) >> 2;

    for (int w = waveGlobal; w < nQuads; w += totalWaves) {
        int e = w * 4 + sub;
        float p = 0.f;
        bool valid = (e < E);
        if (valid) {
            int s = idx[e];
            int t = idx[E + e];
            uint4 za = ((const uint4*)(Zb + (size_t)s * D))[l];
            uint4 xa = ((const uint4*)(XTb + (size_t)t * D))[l];
            p  = __uint_as_float(za.x << 16) * __uint_as_float(xa.x << 16);
            p += __uint_as_float(za.x & 0xffff0000u) * __uint_as_float(xa.x & 0xffff0000u);
            p += __uint_as_float(za.y << 16) * __uint_as_float(xa.y << 16);
            p += __uint_as_float(za.y & 0xffff0000u) * __uint_as_float(xa.y & 0xffff0000u);
            p += __uint_as_float(za.z << 16) * __uint_as_float(xa.z << 16);
            p += __uint_as_float(za.z & 0xffff0000u) * __uint_as_float(xa.z & 0xffff0000u);
            p += __uint_as_float(za.w << 16) * __uint_as_float(xa.w << 16);
            p += __uint_as_float(za.w & 0xffff0000u) * __uint_as_float(xa.w & 0xffff0000u);
        }
        p += __shfl_xor(p, 1, 64);
        p += __shfl_xor(p, 2, 64);
        p += __shfl_xor(p, 4, 64);
        p += __shfl_xor(p, 8, 64);
        if (l == 0 && valid) out[e] = p + b;
    }
}

extern "C" void kernel_launch(void* const* d_in, const int* in_sizes, int n_in,
                              void* d_out, int out_size, void* d_ws, size_t ws_size,
                              hipStream_t stream) {
    const float* x_source = (const float*)d_in[0];
    const float* x_target = (const float*)d_in[1];
    const int* edge_idx = (const int*)d_in[2];
    const float* W = (const float*)d_in[3];
    const float* b = (const float*)d_in[4];
    float* out = (float*)d_out;

    const int N = in_sizes[0] / D;           // 100000
    const int E = in_sizes[2] / 2;           // 2000000

    unsigned short* Zb = (unsigned short*)d_ws;                    // [N,128] bf16
    unsigned short* XTb = Zb + (size_t)N * D;                      // [N,128] bf16

    // Zb = bf16(x_source @ W)
    int gemm_blocks = (N + 63) / 64;
    gemm_xw<<<gemm_blocks, 256, 0, stream>>>(x_source, W, Zb, N);

    // XTb = bf16(x_target)
    int n8 = N * D / 8;
    cast_to_bf16<<<2048, 256, 0, stream>>>(x_target, XTb, n8);

    // edge scores
    edge_score<<<2048, 256, 0, stream>>>(Zb, XTb, edge_idx, b, out, E);
}

// Round 3
// 178.845 us; speedup vs baseline: 1.8483x; 1.1351x over previous
//
#include <hip/hip_runtime.h>
#include <hip/hip_bf16.h>

// Bilinear edge scoring:  out[e] = x_source[src[e]] @ W @ x_target[tgt[e]] + b
// Factored: Zb = bf16(x_source @ W) via bf16 MFMA GEMM (fp32 accum),
//           XTb = bf16(x_target),
//           out[e] = dot(Zb[src[e]], XTb[tgt[e]]) + b  (fp32 accum).
// Edge gather is L2-miss-path bound; idx/out streams marked nontemporal to
// preserve L2 for the 51 MB gather working set.

#define D 128

typedef short bf16x8 __attribute__((ext_vector_type(8)));   // 8 bf16 = 4 VGPR
typedef float f32x4 __attribute__((ext_vector_type(4)));

__device__ __forceinline__ unsigned short f2bf_rn(float f) {
    unsigned int u = __float_as_uint(f);
    u += 0x7fff + ((u >> 16) & 1);          // round-to-nearest-even
    return (unsigned short)(u >> 16);
}
__device__ __forceinline__ unsigned int pack2bf(float a, float b) {
    return (unsigned int)f2bf_rn(a) | ((unsigned int)f2bf_rn(b) << 16);
}

// ---------------------------------------------------------------------------
// Kernel 0: Wtb[n][k] = bf16(W[k][n])   (128x128, one-time transpose+cast)
// ---------------------------------------------------------------------------
__global__ __launch_bounds__(256) void wt_cast(const float* __restrict__ W,
                                               unsigned short* __restrict__ Wtb) {
    int idx = blockIdx.x * 256 + threadIdx.x;   // 64 blocks x 256 = 16384
    int k = idx >> 7, n = idx & 127;
    Wtb[n * 128 + k] = f2bf_rn(W[idx]);
}

// ---------------------------------------------------------------------------
// Kernel 1: Zb = bf16(X @ W) via mfma_f32_16x16x32_bf16.
// Block = 256 thr (4 waves), tile 64 rows x 128 cols, K=128 in one LDS stage.
// LDS XOR-swizzle (byte ^= (row&7)<<4): rows at 256B stride would otherwise
// 16-way bank-conflict on ds_read_b128 (G4 / T2).
// A-frag: lane holds X[w*16 + (lane&15)][k=(lane>>4)*8 ..+7]
// B-frag: lane holds Wt[nb*16 + (lane&15)][k=(lane>>4)*8 ..+7]
// C/D   : col=lane&15, row=(lane>>4)*4+reg (m89-verified layout).
// ---------------------------------------------------------------------------
__global__ __launch_bounds__(256) void gemm_xw_mfma(const float* __restrict__ X,
                                                    const unsigned short* __restrict__ Wtb,
                                                    unsigned short* __restrict__ Zb, int N) {
    __shared__ unsigned short wls[128 * 128];   // swizzled [n][k] bf16, 32 KB
    __shared__ unsigned short xls[64 * 128];    // swizzled [m][k] bf16, 16 KB

    const int tid = threadIdx.x;
    const int block_row = blockIdx.x * 64;

    // stage Wt (2048 16B chunks, 8/thread), coalesced read, swizzled LDS write
#pragma unroll
    for (int j = 0; j < 8; ++j) {
        int c16 = j * 256 + tid;
        int row = c16 >> 4;                  // n
        int kb = (c16 & 15) << 4;            // byte offset within row
        uint4 v = ((const uint4*)Wtb)[c16];
        *(uint4*)((char*)wls + row * 256 + (kb ^ ((row & 7) << 4))) = v;
    }
    // stage X tile (1024 16B chunks, 4/thread): fp32 read, cast, swizzled write
#pragma unroll
    for (int j = 0; j < 4; ++j) {
        int c16 = j * 256 + tid;
        int row = c16 >> 4;                  // m within tile
        int kb = (c16 & 15) << 4;            // byte offset (bf16) => 8 floats
        int grow = block_row + row;
        float4 f0 = make_float4(0.f, 0.f, 0.f, 0.f), f1 = f0;
        if (grow < N) {
            const float4* src = (const float4*)(X + (size_t)grow * D + (kb >> 1));
            f0 = src[0];
            f1 = src[1];
        }
        uint4 v;
        v.x = pack2bf(f0.x, f0.y);
        v.y = pack2bf(f0.z, f0.w);
        v.z = pack2bf(f1.x, f1.y);
        v.w = pack2bf(f1.z, f1.w);
        *(uint4*)((char*)xls + row * 256 + (kb ^ ((row & 7) << 4))) = v;
    }
    __syncthreads();

    const int lane = tid & 63;
    const int w = tid >> 6;                  // wave 0..3 -> rows w*16..+15
    const int lr = lane & 15;
    const int kg = lane >> 4;                // k-group 0..3

    f32x4 acc[8];
#pragma unroll
    for (int nb = 0; nb < 8; ++nb) acc[nb] = (f32x4){0.f, 0.f, 0.f, 0.f};

    const int arow = w * 16 + lr;
    const int swz = (lr & 7) << 4;
#pragma unroll
    for (int ks = 0; ks < 4; ++ks) {
        int kbyte = ks * 64 + kg * 16;
        bf16x8 a = *(const bf16x8*)((const char*)xls + arow * 256 + (kbyte ^ swz));
#pragma unroll
        for (int nb = 0; nb < 8; ++nb) {
            int nrow = nb * 16 + lr;
            bf16x8 b = *(const bf16x8*)((const char*)wls + nrow * 256 + (kbyte ^ swz));
            acc[nb] = __builtin_amdgcn_mfma_f32_16x16x32_bf16(a, b, acc[nb], 0, 0, 0);
        }
    }

    // epilogue: C/D layout col=lane&15, row=(lane>>4)*4+reg
    const int orow0 = block_row + w * 16 + kg * 4;
#pragma unroll
    for (int nb = 0; nb < 8; ++nb) {
        int col = nb * 16 + lr;
#pragma unroll
        for (int j = 0; j < 4; ++j) {
            int grow = orow0 + j;
            if (grow < N) Zb[(size_t)grow * D + col] = f2bf_rn(acc[nb][j]);
        }
    }
}

// ---------------------------------------------------------------------------
// Kernel 2: streaming fp32 -> bf16 cast (8 elements / thread / iter)
// ---------------------------------------------------------------------------
__global__ __launch_bounds__(256) void cast_to_bf16(const float* __restrict__ in,
                                                    unsigned short* __restrict__ outb,
                                                    int n8) {
    int i = blockIdx.x * blockDim.x + threadIdx.x;
    const int stride = gridDim.x * blockDim.x;
    for (; i < n8; i += stride) {
        float4 a = ((const float4*)in)[2 * i];
        float4 c = ((const float4*)in)[2 * i + 1];
        uint4 o;
        o.x = pack2bf(a.x, a.y);
        o.y = pack2bf(a.z, a.w);
        o.z = pack2bf(c.x, c.y);
        o.w = pack2bf(c.z, c.w);
        ((uint4*)outb)[i] = o;
    }
}

// ---------------------------------------------------------------------------
// Kernel 3: out[e] = dot(Zb[src[e]], XTb[tgt[e]]) + b
// 16 lanes/edge, one uint4 (8 bf16) per lane, 4x shfl_xor reduce, 4 edges/wave.
// idx/out use nontemporal hints to keep L2 capacity for the gather rows.
// ---------------------------------------------------------------------------
__global__ __launch_bounds__(256) void edge_score(const unsigned short* __restrict__ Zb,
                                                  const unsigned short* __restrict__ XTb,
                                                  const int* __restrict__ idx,
                                                  const float* __restrict__ bptr,
                                                  float* __restrict__ out, int E) {
    const float b = bptr[0];
    const int lane = threadIdx.x & 63;
    const int sub = lane >> 4;
    const int l = lane & 15;
    const int waveGlobal = blockIdx.x * 4 + (threadIdx.x >> 6);
    const int totalWaves = gridDim.x * 4;
    const int nQuads = (E + 3) >> 2;

    for (int w = waveGlobal; w < nQuads; w += totalWaves) {
        int e = w * 4 + sub;
        float p = 0.f;
        bool valid = (e < E);
        if (valid) {
            int s = __builtin_nontemporal_load(&idx[e]);
            int t = __builtin_nontemporal_load(&idx[E + e]);
            uint4 za = ((const uint4*)(Zb + (size_t)s * D))[l];
            uint4 xa = ((const uint4*)(XTb + (size_t)t * D))[l];
            p  = __uint_as_float(za.x << 16) * __uint_as_float(xa.x << 16);
            p += __uint_as_float(za.x & 0xffff0000u) * __uint_as_float(xa.x & 0xffff0000u);
            p += __uint_as_float(za.y << 16) * __uint_as_float(xa.y << 16);
            p += __uint_as_float(za.y & 0xffff0000u) * __uint_as_float(xa.y & 0xffff0000u);
            p += __uint_as_float(za.z << 16) * __uint_as_float(xa.z << 16);
            p += __uint_as_float(za.z & 0xffff0000u) * __uint_as_float(xa.z & 0xffff0000u);
            p += __uint_as_float(za.w << 16) * __uint_as_float(xa.w << 16);
            p += __uint_as_float(za.w & 0xffff0000u) * __uint_as_float(xa.w & 0xffff0000u);
        }
        p += __shfl_xor(p, 1, 64);
        p += __shfl_xor(p, 2, 64);
        p += __shfl_xor(p, 4, 64);
        p += __shfl_xor(p, 8, 64);
        if (l == 0 && valid) __builtin_nontemporal_store(p + b, &out[e]);
    }
}

extern "C" void kernel_launch(void* const* d_in, const int* in_sizes, int n_in,
                              void* d_out, int out_size, void* d_ws, size_t ws_size,
                              hipStream_t stream) {
    const float* x_source = (const float*)d_in[0];
    const float* x_target = (const float*)d_in[1];
    const int* edge_idx = (const int*)d_in[2];
    const float* W = (const float*)d_in[3];
    const float* b = (const float*)d_in[4];
    float* out = (float*)d_out;

    const int N = in_sizes[0] / D;           // 100000
    const int E = in_sizes[2] / 2;           // 2000000

    unsigned short* Zb = (unsigned short*)d_ws;          // [N,128] bf16
    unsigned short* XTb = Zb + (size_t)N * D;            // [N,128] bf16
    unsigned short* Wtb = XTb + (size_t)N * D;           // [128,128] bf16

    // W^T cast (B-operand wants [n][k])
    wt_cast<<<64, 256, 0, stream>>>(W, Wtb);

    // XTb = bf16(x_target)
    cast_to_bf16<<<2048, 256, 0, stream>>>(x_target, XTb, N * D / 8);

    // Zb = bf16(x_source @ W)  (MFMA)
    gemm_xw_mfma<<<(N + 63) / 64, 256, 0, stream>>>(x_source, Wtb, Zb, N);

    // edge scores
    edge_score<<<2048, 256, 0, stream>>>(Zb, XTb, edge_idx, b, out, E);
}